// Round 1
// baseline (41660.565 us; speedup 1.0000x reference)
//
#include <hip/hip_runtime.h>

// SGLC encoder: T=64, B=32, N=64, DIN=H=128, 2 layers, dynamic supports.
// Strategy: batches are independent -> 1 workgroup per batch (32 WGs x 1024 thr),
// whole recurrence in ONE kernel launch. fp32 correctness baseline.
#define TT 64
#define BB 32
#define NN 64
#define HH 128
#define NH 8192      // N*H == N*DIN
#define WSB 20480    // per-batch ws floats: T(8192) + RH(8192) + Sup(4096)

// Cooperative load of a 64x128 fp32 weight tile into LDS.
__device__ __forceinline__ void wtile_load(const float* __restrict__ Wt, int ldw,
                                           float* sWp, int tid) {
  const int r  = tid >> 4;          // 0..63 tile row
  const int c8 = (tid & 15) << 3;   // 0..120 col start
  const float* src = Wt + (size_t)r * ldw + c8;
  const float4 w0 = *(const float4*)(src);
  const float4 w1 = *(const float4*)(src + 4);
  *(float4*)(sWp + r * 128 + c8)     = w0;
  *(float4*)(sWp + r * 128 + c8 + 4) = w1;
}

// acc[0..7] += A[row, k0..k0+63] dot sW[0..63][g0..g0+7]
__device__ __forceinline__ void gemm_tile64(const float* __restrict__ arow,
                                            const float* __restrict__ sWp,
                                            int g0, float* __restrict__ acc) {
#pragma unroll
  for (int kt = 0; kt < 64; kt += 4) {
    const float4 a4 = *(const float4*)(arow + kt);
    float av[4] = {a4.x, a4.y, a4.z, a4.w};
#pragma unroll
    for (int i = 0; i < 4; ++i) {
      const float* wr = sWp + (kt + i) * 128 + g0;
      const float4 w0 = *(const float4*)(wr);
      const float4 w1 = *(const float4*)(wr + 4);
      acc[0] += av[i] * w0.x; acc[1] += av[i] * w0.y;
      acc[2] += av[i] * w0.z; acc[3] += av[i] * w0.w;
      acc[4] += av[i] * w1.x; acc[5] += av[i] * w1.y;
      acc[6] += av[i] * w1.z; acc[7] += av[i] * w1.w;
    }
  }
}

extern "C" __global__ void __launch_bounds__(1024)
sglc_fused(const float* __restrict__ Xin, const float* __restrict__ H0,
           const float* __restrict__ Sup0,
           const float* __restrict__ Wg0, const float* __restrict__ bg0,
           const float* __restrict__ Wc0, const float* __restrict__ bc0,
           const float* __restrict__ Wq0, const float* __restrict__ Wk0,
           const float* __restrict__ Wg1, const float* __restrict__ bg1,
           const float* __restrict__ Wc1, const float* __restrict__ bc1,
           const float* __restrict__ Wq1, const float* __restrict__ Wk1,
           float* __restrict__ Out, float* __restrict__ Ws) {
  __shared__ float sH[NN * HH];     // 32 KB hidden state (persistent per layer)
  __shared__ float sW[64 * 128];    // 32 KB weight tile

  const int b   = blockIdx.x;
  const int tid = threadIdx.x;
  const int n   = tid >> 4;          // 0..63 node (output row)
  const int g0  = (tid & 15) << 3;   // 0..120 output col start (8 cols/thread)

  float* OutH = Out;                       // (2, B, 8192)
  float* Cur  = Out + 2 * BB * NH;         // (T, B, 8192): layer0 hs scratch, then layer1 hs
  float* wsT   = Ws + (size_t)b * WSB;     // 64x128 temp
  float* wsRH  = wsT + 8192;               // 64x128 r*h / k
  float* wsSup = wsT + 16384;              // 64x64 supports (carried across layers)

  for (int layer = 0; layer < 2; ++layer) {
    const float* Wg = layer ? Wg1 : Wg0;
    const float* bg = layer ? bg1 : bg0;
    const float* Wc = layer ? Wc1 : Wc0;
    const float* bc = layer ? bc1 : bc0;
    const float* Wq = layer ? Wq1 : Wq0;
    const float* Wk = layer ? Wk1 : Wk0;
    const float* xbase = layer ? Cur : Xin;

    const float* h0 = H0 + (size_t)(layer * BB + b) * NH;
    for (int i = tid; i < NH; i += 1024) sH[i] = h0[i];
    if (layer == 0) {
      const float* s0 = Sup0 + (size_t)b * (NN * NN);
      for (int i = tid; i < NN * NN; i += 1024) wsSup[i] = s0[i];
    }
    __syncthreads();

    for (int t = 0; t < TT; ++t) {
      const float* gx = xbase + (size_t)(t * BB + b) * NH;  // x_t rows: n*128+k
      float u_reg[8];

      // ---- A0: wsT = xh @ Wg[256:512, 0:128]   (xh = [x | h])
      {
        float acc[8] = {0, 0, 0, 0, 0, 0, 0, 0};
        for (int k0 = 0; k0 < 256; k0 += 64) {
          __syncthreads();
          wtile_load(Wg + (size_t)(256 + k0) * 256 + 0, 256, sW, tid);
          __syncthreads();
          if (k0 < 128) gemm_tile64(gx + n * 128 + k0, sW, g0, acc);
          else          gemm_tile64(&sH[n * 128 + (k0 - 128)], sW, g0, acc);
        }
        float4 o0 = {acc[0], acc[1], acc[2], acc[3]};
        float4 o1 = {acc[4], acc[5], acc[6], acc[7]};
        *(float4*)(&wsT[n * 128 + g0])     = o0;
        *(float4*)(&wsT[n * 128 + g0 + 4]) = o1;
      }
      // ---- B0: r = sigmoid(xh@Wg[0:256,0:128] + sup@wsT + bg[0:128]); wsRH = r*h
      {
        float acc[8] = {0, 0, 0, 0, 0, 0, 0, 0};
        for (int k0 = 0; k0 < 256; k0 += 64) {
          __syncthreads();
          wtile_load(Wg + (size_t)k0 * 256 + 0, 256, sW, tid);
          __syncthreads();
          if (k0 < 128) gemm_tile64(gx + n * 128 + k0, sW, g0, acc);
          else          gemm_tile64(&sH[n * 128 + (k0 - 128)], sW, g0, acc);
        }
#pragma unroll 8
        for (int m = 0; m < 64; ++m) {
          const float s = wsSup[n * 64 + m];
          const float* tr = wsT + m * 128 + g0;
          const float4 t0 = *(const float4*)(tr);
          const float4 t1 = *(const float4*)(tr + 4);
          acc[0] += s * t0.x; acc[1] += s * t0.y; acc[2] += s * t0.z; acc[3] += s * t0.w;
          acc[4] += s * t1.x; acc[5] += s * t1.y; acc[6] += s * t1.z; acc[7] += s * t1.w;
        }
        float rh[8];
#pragma unroll
        for (int j = 0; j < 8; ++j) {
          const float rv = 1.0f / (1.0f + __expf(-(acc[j] + bg[g0 + j])));
          rh[j] = rv * sH[n * 128 + g0 + j];
        }
        float4 o0 = {rh[0], rh[1], rh[2], rh[3]};
        float4 o1 = {rh[4], rh[5], rh[6], rh[7]};
        *(float4*)(&wsRH[n * 128 + g0])     = o0;
        *(float4*)(&wsRH[n * 128 + g0 + 4]) = o1;
      }
      // ---- A1: wsT = xh @ Wg[256:512, 128:256]
      {
        float acc[8] = {0, 0, 0, 0, 0, 0, 0, 0};
        for (int k0 = 0; k0 < 256; k0 += 64) {
          __syncthreads();
          wtile_load(Wg + (size_t)(256 + k0) * 256 + 128, 256, sW, tid);
          __syncthreads();
          if (k0 < 128) gemm_tile64(gx + n * 128 + k0, sW, g0, acc);
          else          gemm_tile64(&sH[n * 128 + (k0 - 128)], sW, g0, acc);
        }
        float4 o0 = {acc[0], acc[1], acc[2], acc[3]};
        float4 o1 = {acc[4], acc[5], acc[6], acc[7]};
        *(float4*)(&wsT[n * 128 + g0])     = o0;
        *(float4*)(&wsT[n * 128 + g0 + 4]) = o1;
      }
      // ---- B1: u = sigmoid(xh@Wg[0:256,128:256] + sup@wsT + bg[128:256]) -> registers
      {
        float acc[8] = {0, 0, 0, 0, 0, 0, 0, 0};
        for (int k0 = 0; k0 < 256; k0 += 64) {
          __syncthreads();
          wtile_load(Wg + (size_t)k0 * 256 + 128, 256, sW, tid);
          __syncthreads();
          if (k0 < 128) gemm_tile64(gx + n * 128 + k0, sW, g0, acc);
          else          gemm_tile64(&sH[n * 128 + (k0 - 128)], sW, g0, acc);
        }
#pragma unroll 8
        for (int m = 0; m < 64; ++m) {
          const float s = wsSup[n * 64 + m];
          const float* tr = wsT + m * 128 + g0;
          const float4 t0 = *(const float4*)(tr);
          const float4 t1 = *(const float4*)(tr + 4);
          acc[0] += s * t0.x; acc[1] += s * t0.y; acc[2] += s * t0.z; acc[3] += s * t0.w;
          acc[4] += s * t1.x; acc[5] += s * t1.y; acc[6] += s * t1.z; acc[7] += s * t1.w;
        }
#pragma unroll
        for (int j = 0; j < 8; ++j)
          u_reg[j] = 1.0f / (1.0f + __expf(-(acc[j] + bg[128 + g0 + j])));
      }
      // ---- E: wsT = xh_r @ Wc[256:512, :]   (xh_r = [x | r*h])
      {
        float acc[8] = {0, 0, 0, 0, 0, 0, 0, 0};
        for (int k0 = 0; k0 < 256; k0 += 64) {
          __syncthreads();
          wtile_load(Wc + (size_t)(256 + k0) * 128, 128, sW, tid);
          __syncthreads();
          if (k0 < 128) gemm_tile64(gx + n * 128 + k0, sW, g0, acc);
          else          gemm_tile64(wsRH + n * 128 + (k0 - 128), sW, g0, acc);
        }
        float4 o0 = {acc[0], acc[1], acc[2], acc[3]};
        float4 o1 = {acc[4], acc[5], acc[6], acc[7]};
        *(float4*)(&wsT[n * 128 + g0])     = o0;
        *(float4*)(&wsT[n * 128 + g0 + 4]) = o1;
      }
      // ---- F: c = tanh(xh_r@Wc[0:256] + sup@wsT + bc); h_new = u*h + (1-u)*c
      {
        float acc[8] = {0, 0, 0, 0, 0, 0, 0, 0};
        for (int k0 = 0; k0 < 256; k0 += 64) {
          __syncthreads();
          wtile_load(Wc + (size_t)k0 * 128, 128, sW, tid);
          __syncthreads();
          if (k0 < 128) gemm_tile64(gx + n * 128 + k0, sW, g0, acc);
          else          gemm_tile64(wsRH + n * 128 + (k0 - 128), sW, g0, acc);
        }
#pragma unroll 8
        for (int m = 0; m < 64; ++m) {
          const float s = wsSup[n * 64 + m];
          const float* tr = wsT + m * 128 + g0;
          const float4 t0 = *(const float4*)(tr);
          const float4 t1 = *(const float4*)(tr + 4);
          acc[0] += s * t0.x; acc[1] += s * t0.y; acc[2] += s * t0.z; acc[3] += s * t0.w;
          acc[4] += s * t1.x; acc[5] += s * t1.y; acc[6] += s * t1.z; acc[7] += s * t1.w;
        }
        float hn[8];
#pragma unroll
        for (int j = 0; j < 8; ++j) {
          const float cv = tanhf(acc[j] + bc[g0 + j]);
          const float hv = sH[n * 128 + g0 + j];
          hn[j] = u_reg[j] * hv + (1.0f - u_reg[j]) * cv;
        }
        __syncthreads();  // all reads of gx/wsRH/sH done before in-place updates
#pragma unroll
        for (int j = 0; j < 8; ++j) sH[n * 128 + g0 + j] = hn[j];
        float4 o0 = {hn[0], hn[1], hn[2], hn[3]};
        float4 o1 = {hn[4], hn[5], hn[6], hn[7]};
        float* crow = Cur + (size_t)(t * BB + b) * NH + n * 128 + g0;
        *(float4*)(crow)     = o0;
        *(float4*)(crow + 4) = o1;
        if (t == TT - 1) {
          float* orow = OutH + (size_t)(layer * BB + b) * NH + n * 128 + g0;
          *(float4*)(orow)     = o0;
          *(float4*)(orow + 4) = o1;
        }
      }
      // ---- G: q = h_new@Wq -> wsT ; k = h_new@Wk -> wsRH
      {
        float accq[8] = {0, 0, 0, 0, 0, 0, 0, 0};
        float acck[8] = {0, 0, 0, 0, 0, 0, 0, 0};
        for (int k0 = 0; k0 < 128; k0 += 64) {
          __syncthreads();
          wtile_load(Wq + (size_t)k0 * 128, 128, sW, tid);
          __syncthreads();
          gemm_tile64(&sH[n * 128 + k0], sW, g0, accq);
        }
        for (int k0 = 0; k0 < 128; k0 += 64) {
          __syncthreads();
          wtile_load(Wk + (size_t)k0 * 128, 128, sW, tid);
          __syncthreads();
          gemm_tile64(&sH[n * 128 + k0], sW, g0, acck);
        }
        float4 q0 = {accq[0], accq[1], accq[2], accq[3]};
        float4 q1 = {accq[4], accq[5], accq[6], accq[7]};
        *(float4*)(&wsT[n * 128 + g0])     = q0;
        *(float4*)(&wsT[n * 128 + g0 + 4]) = q1;
        float4 kk0 = {acck[0], acck[1], acck[2], acck[3]};
        float4 kk1 = {acck[4], acck[5], acck[6], acck[7]};
        *(float4*)(&wsRH[n * 128 + g0])     = kk0;
        *(float4*)(&wsRH[n * 128 + g0 + 4]) = kk1;
      }
      // ---- H: scores = q@k^T, relu, row-softmax -> wsSup
      {
        __syncthreads();  // make q/k visible
        const int mi = tid & 15;
        float s0 = 0.f, s1 = 0.f, s2 = 0.f, s3 = 0.f;
        const float* qr = wsT + n * 128;
        const float* kr = wsRH + (size_t)(mi * 4) * 128;
#pragma unroll 4
        for (int d = 0; d < 128; d += 4) {
          const float4 qv = *(const float4*)(qr + d);
          const float4 k0v = *(const float4*)(kr + 0 * 128 + d);
          const float4 k1v = *(const float4*)(kr + 1 * 128 + d);
          const float4 k2v = *(const float4*)(kr + 2 * 128 + d);
          const float4 k3v = *(const float4*)(kr + 3 * 128 + d);
          s0 += qv.x * k0v.x + qv.y * k0v.y + qv.z * k0v.z + qv.w * k0v.w;
          s1 += qv.x * k1v.x + qv.y * k1v.y + qv.z * k1v.z + qv.w * k1v.w;
          s2 += qv.x * k2v.x + qv.y * k2v.y + qv.z * k2v.z + qv.w * k2v.w;
          s3 += qv.x * k3v.x + qv.y * k3v.y + qv.z * k3v.z + qv.w * k3v.w;
        }
        s0 = fmaxf(s0, 0.f); s1 = fmaxf(s1, 0.f);
        s2 = fmaxf(s2, 0.f); s3 = fmaxf(s3, 0.f);
        float mx = fmaxf(fmaxf(s0, s1), fmaxf(s2, s3));
#pragma unroll
        for (int off = 1; off < 16; off <<= 1) mx = fmaxf(mx, __shfl_xor(mx, off, 16));
        const float e0 = __expf(s0 - mx), e1 = __expf(s1 - mx);
        const float e2 = __expf(s2 - mx), e3 = __expf(s3 - mx);
        float sum = e0 + e1 + e2 + e3;
#pragma unroll
        for (int off = 1; off < 16; off <<= 1) sum += __shfl_xor(sum, off, 16);
        const float inv = 1.0f / sum;
        float4 sv = {e0 * inv, e1 * inv, e2 * inv, e3 * inv};
        *(float4*)(&wsSup[n * 64 + mi * 4]) = sv;
        __syncthreads();
      }
    }  // t
    __syncthreads();
  }  // layer
}

extern "C" void kernel_launch(void* const* d_in, const int* in_sizes, int n_in,
                              void* d_out, int out_size, void* d_ws, size_t ws_size,
                              hipStream_t stream) {
  const float* Xin  = (const float*)d_in[0];
  const float* H0   = (const float*)d_in[1];
  const float* Sup0 = (const float*)d_in[2];
  const float* Wg0  = (const float*)d_in[3];
  const float* bg0  = (const float*)d_in[4];
  const float* Wc0  = (const float*)d_in[5];
  const float* bc0  = (const float*)d_in[6];
  const float* Wq0  = (const float*)d_in[7];
  const float* Wk0  = (const float*)d_in[8];
  const float* Wg1  = (const float*)d_in[9];
  const float* bg1  = (const float*)d_in[10];
  const float* Wc1  = (const float*)d_in[11];
  const float* bc1  = (const float*)d_in[12];
  const float* Wq1  = (const float*)d_in[13];
  const float* Wk1  = (const float*)d_in[14];
  hipLaunchKernelGGL(sglc_fused, dim3(BB), dim3(1024), 0, stream,
                     Xin, H0, Sup0,
                     Wg0, bg0, Wc0, bc0, Wq0, Wk0,
                     Wg1, bg1, Wc1, bc1, Wq1, Wk1,
                     (float*)d_out, (float*)d_ws);
}

// Round 2
// 3455.764 us; speedup vs baseline: 12.0554x; 12.0554x over previous
//
#include <hip/hip_runtime.h>

// SGLC encoder on MI355X: T=64, B=32, N=64, DIN=H=128, 2 layers, dynamic supports.
// One workgroup per batch chain (32 blocks x 1024 thr), bf16 MFMA 32x32x16,
// fragment-packed weights streamed from L2, all activations in LDS.
#define TT 64
#define BB 32
#define NN 64
#define HH 128
#define NH 8192

using short8 = __attribute__((ext_vector_type(8))) short;
using f32x16 = __attribute__((ext_vector_type(16))) float;

__device__ __forceinline__ unsigned short f2bf(float f) {
  unsigned int u = __float_as_uint(f);
  u = (u + 0x7FFFu + ((u >> 16) & 1u)) >> 16;
  return (unsigned short)u;
}
__device__ __forceinline__ float bf2f(unsigned short s) {
  return __uint_as_float(((unsigned int)s) << 16);
}
__device__ __forceinline__ float sigm(float x) { return 1.0f / (1.0f + __expf(-x)); }
__device__ __forceinline__ float tanh_fast(float x) { return 2.0f / (1.0f + __expf(-2.0f * x)) - 1.0f; }

__device__ __forceinline__ uint2 pack4(float a, float b, float c, float d) {
  uint2 r;
  r.x = (unsigned int)f2bf(a) | ((unsigned int)f2bf(b) << 16);
  r.y = (unsigned int)f2bf(c) | ((unsigned int)f2bf(d) << 16);
  return r;
}
// LDS fragment load: 8 bf16 at 8B-aligned address (row strides chosen = 2 banks -> conflict-free)
__device__ __forceinline__ short8 ldsfrag(const unsigned short* p) {
  union { uint2 u2[2]; short8 s; } f;
  f.u2[0] = *(const uint2*)p;
  f.u2[1] = *(const uint2*)(p + 4);
  return f.s;
}
// Global fragment load: 16B coalesced from fragment-packed weights
__device__ __forceinline__ short8 ldgfrag(const unsigned short* p) {
  union { uint4 u4; short8 s; } f;
  f.u4 = *(const uint4*)p;
  return f.s;
}

// ---- weight packing: fp32 W[k][c] -> bf16 fragment-major blocks of 512 ushorts per (c32,kc):
// packed[((c32*nkc + kc)<<9) + lane*8 + j] = bf16(W[kc*16 + (lane>>5)*8 + j][c32*32 + (lane&31)])
// Regions per layer (ushort offsets): Wg 0 (nkc=32,ncols=256), Wc 131072 (32,128), Wq 196608 (8,128), Wk 212992 (8,128)
__global__ void sglc_pack(const float* __restrict__ Wg0, const float* __restrict__ Wc0,
                          const float* __restrict__ Wq0, const float* __restrict__ Wk0,
                          const float* __restrict__ Wg1, const float* __restrict__ Wc1,
                          const float* __restrict__ Wq1, const float* __restrict__ Wk1,
                          unsigned short* __restrict__ dst) {
  int idx = blockIdx.x * 256 + threadIdx.x;
  if (idx >= 458752) return;
  int layer = idx / 229376;
  int lo = idx - layer * 229376;
  const float* src; int nkc, ncshift, off;
  if (lo < 131072)      { src = layer ? Wg1 : Wg0; nkc = 32; ncshift = 8; off = 0; }
  else if (lo < 196608) { src = layer ? Wc1 : Wc0; nkc = 32; ncshift = 7; off = 131072; }
  else if (lo < 212992) { src = layer ? Wq1 : Wq0; nkc = 8;  ncshift = 7; off = 196608; }
  else                  { src = layer ? Wk1 : Wk0; nkc = 8;  ncshift = 7; off = 212992; }
  int l2 = lo - off;
  int k = l2 >> ncshift;
  int c = l2 & ((1 << ncshift) - 1);
  int c32 = c >> 5, n32 = c & 31;
  int kc = k >> 4, kl = k & 15;
  int half = kl >> 3, j = kl & 7;
  int lane = half * 32 + n32;
  int dstoff = layer * 229376 + off + (((c32 * nkc + kc) << 9) + lane * 8 + j);
  dst[dstoff] = f2bf(src[(size_t)k * (1 << ncshift) + c]);
}

// LDS layout (ushort offsets), all bf16 row stride 132 (A-arrays) / 68 (sup, PT):
#define SX_O   0
#define SH_O   8448
#define SRH_O  16896
#define SQ_O   25344
#define SK_O   33792
#define SSUP_O 42240
#define SPT_O  46592
#define LDS_USHORTS 64000  // 128000 bytes

extern "C" __global__ void __launch_bounds__(1024, 4)
sglc_main(const float* __restrict__ Xin, const float* __restrict__ H0,
          const float* __restrict__ Sup0,
          const float* __restrict__ bg0, const float* __restrict__ bc0,
          const float* __restrict__ bg1, const float* __restrict__ bc1,
          const unsigned short* __restrict__ Wp, float* __restrict__ Out) {
  extern __shared__ unsigned short sm[];
  unsigned short* sX   = sm + SX_O;
  unsigned short* sHb  = sm + SH_O;
  unsigned short* sRH  = sm + SRH_O;
  unsigned short* sQ   = sm + SQ_O;
  unsigned short* sK   = sm + SK_O;
  unsigned short* sSup = sm + SSUP_O;
  unsigned short* sPT  = sm + SPT_O;
  float* sS = (float*)(sm + SPT_O);  // overlays sPT (disjoint in time within a step)

  const int b = blockIdx.x;
  const int tid = threadIdx.x;
  const int lane = tid & 63;
  const int w = tid >> 6;
  const int n32 = lane & 31;
  const int half = lane >> 5;
  const int kob = half * 8;

  float* OutH = Out;
  float* Cur  = Out + 2 * BB * NH;

  float h_reg[32];  // fp32 master of h, meaningful on waves 4..7 (C-layout positions)

  for (int layer = 0; layer < 2; ++layer) {
    const int Lw = layer * 229376;
    const float* bg = layer ? bg1 : bg0;
    const float* bc = layer ? bc1 : bc0;
    const float* xbase = layer ? Cur : Xin;
    const float* h0p = H0 + (size_t)(layer * BB + b) * NH;

    const float bgv = (w < 8) ? bg[(w & 7) * 32 + n32] : 0.0f;
    const float bcv = (w >= 4 && w < 8) ? bc[(w - 4) * 32 + n32] : 0.0f;

    // ---- layer init: stage h0 (bf16), h_reg (fp32), sup (layer 0), x_0 ----
    {
      int r = tid >> 4, c0 = (tid & 15) * 8;
      const float* hp = h0p + r * 128 + c0;
      float4 v0 = *(const float4*)(hp);
      float4 v1 = *(const float4*)(hp + 4);
      *(uint2*)(sHb + r * 132 + c0)     = pack4(v0.x, v0.y, v0.z, v0.w);
      *(uint2*)(sHb + r * 132 + c0 + 4) = pack4(v1.x, v1.y, v1.z, v1.w);
      const float* xp = xbase + (size_t)(0 * BB + b) * NH + r * 128 + c0;
      float4 x0 = *(const float4*)(xp);
      float4 x1 = *(const float4*)(xp + 4);
      *(uint2*)(sX + r * 132 + c0)     = pack4(x0.x, x0.y, x0.z, x0.w);
      *(uint2*)(sX + r * 132 + c0 + 4) = pack4(x1.x, x1.y, x1.z, x1.w);
      if (layer == 0) {
        int rs = tid >> 4, cs = (tid & 15) * 4;
        float4 sv = *(const float4*)(Sup0 + (size_t)b * 4096 + rs * 64 + cs);
        *(uint2*)(sSup + rs * 68 + cs) = pack4(sv.x, sv.y, sv.z, sv.w);
      }
    }
    if (w >= 4 && w < 8) {
      const int col = (w - 4) * 32 + n32;
#pragma unroll
      for (int tt = 0; tt < 2; ++tt)
#pragma unroll
        for (int g = 0; g < 4; ++g)
#pragma unroll
          for (int i = 0; i < 4; ++i)
            h_reg[tt * 16 + 4 * g + i] = h0p[(tt * 32 + 8 * g + 4 * half + i) * 128 + col];
    }
    __syncthreads();

    for (int t = 0; t < TT; ++t) {
      union { float u[32]; short8 bq[8]; } su_;  // exclusive by wave role
      f32x16 acc0, acc1;
#pragma unroll
      for (int z = 0; z < 16; ++z) { acc0[z] = 0.0f; acc1[z] = 0.0f; }

      // ===== gates GEMM: P1 = xh@Wg[0:256,:] (w0-7), P2 = xh@Wg[256:512,:] (w8-15) =====
      {
        const int c32g = w & 7;
        const unsigned short* wb = Wp + Lw + (((c32g * 32 + (w < 8 ? 0 : 16)) << 9) + lane * 8);
#pragma unroll
        for (int kc = 0; kc < 16; ++kc) {
          const unsigned short* asrc = (kc < 8) ? (sX + kc * 16 + kob) : (sHb + (kc - 8) * 16 + kob);
          short8 a0 = ldsfrag(asrc + n32 * 132);
          short8 a1 = ldsfrag(asrc + (32 + n32) * 132);
          short8 bf = ldgfrag(wb + (kc << 9));
          acc0 = __builtin_amdgcn_mfma_f32_32x32x16_bf16(a0, bf, acc0, 0, 0, 0);
          acc1 = __builtin_amdgcn_mfma_f32_32x32x16_bf16(a1, bf, acc1, 0, 0, 0);
        }
        if (w >= 8) {  // write P2^T (bf16) for the conv
          unsigned short* pb = sPT + (c32g * 32 + n32) * 68;
#pragma unroll
          for (int tt = 0; tt < 2; ++tt) {
            const f32x16& ac = tt ? acc1 : acc0;
#pragma unroll
            for (int g = 0; g < 4; ++g)
              *(uint2*)(pb + tt * 32 + 8 * g + 4 * half) =
                  pack4(ac[4 * g], ac[4 * g + 1], ac[4 * g + 2], ac[4 * g + 3]);
          }
        }
      }
      __syncthreads();  // B1

      // ===== conv r/u (w0-7): acc += sup @ P2 ; w8-15: preload Wq/Wk fragments =====
      if (w < 8) {
        const int c32g = w & 7;
#pragma unroll
        for (int kc2 = 0; kc2 < 4; ++kc2) {
          short8 a0 = ldsfrag(sSup + n32 * 68 + kc2 * 16 + kob);
          short8 a1 = ldsfrag(sSup + (32 + n32) * 68 + kc2 * 16 + kob);
          short8 bf = ldsfrag(sPT + (c32g * 32 + n32) * 68 + kc2 * 16 + kob);
          acc0 = __builtin_amdgcn_mfma_f32_32x32x16_bf16(a0, bf, acc0, 0, 0, 0);
          acc1 = __builtin_amdgcn_mfma_f32_32x32x16_bf16(a1, bf, acc1, 0, 0, 0);
        }
        const int col = (w & 7) * 32 + n32;
        if (w < 4) {  // r -> rh into sRH (bf16)
#pragma unroll
          for (int tt = 0; tt < 2; ++tt) {
            const f32x16& ac = tt ? acc1 : acc0;
#pragma unroll
            for (int g = 0; g < 4; ++g)
#pragma unroll
              for (int i = 0; i < 4; ++i) {
                int row = tt * 32 + 8 * g + 4 * half + i;
                float rv = sigm(ac[4 * g + i] + bgv);
                float hv = bf2f(sHb[row * 132 + col]);
                sRH[row * 132 + col] = f2bf(rv * hv);
              }
          }
        } else {  // u stays in registers (positions match cand tiles)
#pragma unroll
          for (int tt = 0; tt < 2; ++tt) {
            const f32x16& ac = tt ? acc1 : acc0;
#pragma unroll
            for (int g = 0; g < 4; ++g)
#pragma unroll
              for (int i = 0; i < 4; ++i)
                su_.u[tt * 16 + 4 * g + i] = sigm(ac[4 * g + i] + bgv);
          }
        }
      } else {
        const unsigned short* qb =
            Wp + Lw + ((w < 12) ? 196608 : 212992) + ((((w - 8) & 3) * 8) << 9) + lane * 8;
#pragma unroll
        for (int kc = 0; kc < 8; ++kc) su_.bq[kc] = ldgfrag(qb + (kc << 9));
      }
      __syncthreads();  // B2

      // ===== candidate GEMM: Q1 = xh_r@Wc[0:256] (w4-7), Q2 = xh_r@Wc[256:512] (w8-11) =====
      f32x16 ca0, ca1;
#pragma unroll
      for (int z = 0; z < 16; ++z) { ca0[z] = 0.0f; ca1[z] = 0.0f; }
      if (w >= 4 && w < 12) {
        const int c32c = (w < 8) ? (w - 4) : (w - 8);
        const unsigned short* wb = Wp + Lw + 131072 + (((c32c * 32 + (w < 8 ? 0 : 16)) << 9) + lane * 8);
#pragma unroll
        for (int kc = 0; kc < 16; ++kc) {
          const unsigned short* asrc = (kc < 8) ? (sX + kc * 16 + kob) : (sRH + (kc - 8) * 16 + kob);
          short8 a0 = ldsfrag(asrc + n32 * 132);
          short8 a1 = ldsfrag(asrc + (32 + n32) * 132);
          short8 bf = ldgfrag(wb + (kc << 9));
          ca0 = __builtin_amdgcn_mfma_f32_32x32x16_bf16(a0, bf, ca0, 0, 0, 0);
          ca1 = __builtin_amdgcn_mfma_f32_32x32x16_bf16(a1, bf, ca1, 0, 0, 0);
        }
        if (w >= 8) {  // write Q2^T
          unsigned short* pb = sPT + (c32c * 32 + n32) * 68;
#pragma unroll
          for (int tt = 0; tt < 2; ++tt) {
            const f32x16& ac = tt ? ca1 : ca0;
#pragma unroll
            for (int g = 0; g < 4; ++g)
              *(uint2*)(pb + tt * 32 + 8 * g + 4 * half) =
                  pack4(ac[4 * g], ac[4 * g + 1], ac[4 * g + 2], ac[4 * g + 3]);
          }
        }
      }
      __syncthreads();  // B3

      // ===== conv c + h update (w4-7); x_{t+1} staging (w0-3, w12-15) =====
      if (w >= 4 && w < 8) {
        const int c32c = w - 4;
        const int col = c32c * 32 + n32;
#pragma unroll
        for (int kc2 = 0; kc2 < 4; ++kc2) {
          short8 a0 = ldsfrag(sSup + n32 * 68 + kc2 * 16 + kob);
          short8 a1 = ldsfrag(sSup + (32 + n32) * 68 + kc2 * 16 + kob);
          short8 bf = ldsfrag(sPT + col * 68 + kc2 * 16 + kob);
          ca0 = __builtin_amdgcn_mfma_f32_32x32x16_bf16(a0, bf, ca0, 0, 0, 0);
          ca1 = __builtin_amdgcn_mfma_f32_32x32x16_bf16(a1, bf, ca1, 0, 0, 0);
        }
        float* curp = Cur + (size_t)(t * BB + b) * NH;
        float* outp = OutH + (size_t)(layer * BB + b) * NH;
#pragma unroll
        for (int tt = 0; tt < 2; ++tt) {
          const f32x16& ac = tt ? ca1 : ca0;
#pragma unroll
          for (int g = 0; g < 4; ++g)
#pragma unroll
            for (int i = 0; i < 4; ++i) {
              int r16 = tt * 16 + 4 * g + i;
              float cv = tanh_fast(ac[4 * g + i] + bcv);
              float uv = su_.u[r16];
              float hn = uv * h_reg[r16] + (1.0f - uv) * cv;
              h_reg[r16] = hn;
              int row = tt * 32 + 8 * g + 4 * half + i;
              sHb[row * 132 + col] = f2bf(hn);
              curp[row * 128 + col] = hn;
              if (t == TT - 1) outp[row * 128 + col] = hn;
            }
        }
      } else if (w < 4 || w >= 12) {
        if (t < TT - 1) {  // stage x_{t+1}
          const float* xn = xbase + (size_t)((t + 1) * BB + b) * NH;
          int sidx = (w < 4 ? w : w - 8) * 64 + lane;  // 0..511, 16 elems each
          int r = sidx >> 3, c0 = (sidx & 7) * 16;
          const float* sp = xn + r * 128 + c0;
          unsigned short* dp = sX + r * 132 + c0;
#pragma unroll
          for (int q4 = 0; q4 < 4; ++q4) {
            float4 v = *(const float4*)(sp + q4 * 4);
            *(uint2*)(dp + q4 * 4) = pack4(v.x, v.y, v.z, v.w);
          }
        }
      }
      __syncthreads();  // B4

      // ===== q = h@Wq (w8-11), k = h@Wk (w12-15), B-frags preloaded =====
      if (w >= 8) {
        const int col = ((w - 8) & 3) * 32 + n32;
        f32x16 qa0, qa1;
#pragma unroll
        for (int z = 0; z < 16; ++z) { qa0[z] = 0.0f; qa1[z] = 0.0f; }
#pragma unroll
        for (int kc = 0; kc < 8; ++kc) {
          short8 a0 = ldsfrag(sHb + n32 * 132 + kc * 16 + kob);
          short8 a1 = ldsfrag(sHb + (32 + n32) * 132 + kc * 16 + kob);
          qa0 = __builtin_amdgcn_mfma_f32_32x32x16_bf16(a0, su_.bq[kc], qa0, 0, 0, 0);
          qa1 = __builtin_amdgcn_mfma_f32_32x32x16_bf16(a1, su_.bq[kc], qa1, 0, 0, 0);
        }
        unsigned short* dstm = (w < 12) ? sQ : sK;
#pragma unroll
        for (int tt = 0; tt < 2; ++tt) {
          const f32x16& ac = tt ? qa1 : qa0;
#pragma unroll
          for (int g = 0; g < 4; ++g)
#pragma unroll
            for (int i = 0; i < 4; ++i)
              dstm[(tt * 32 + 8 * g + 4 * half + i) * 132 + col] = f2bf(ac[4 * g + i]);
        }
      }
      __syncthreads();  // B5

      // ===== scores = q @ k^T, relu (w0-3) =====
      if (w < 4) {
        const int rt = w & 1, ct = w >> 1;
        f32x16 sa;
#pragma unroll
        for (int z = 0; z < 16; ++z) sa[z] = 0.0f;
#pragma unroll
        for (int kc = 0; kc < 8; ++kc) {
          short8 a0 = ldsfrag(sQ + (rt * 32 + n32) * 132 + kc * 16 + kob);
          short8 bf = ldsfrag(sK + (ct * 32 + n32) * 132 + kc * 16 + kob);
          sa = __builtin_amdgcn_mfma_f32_32x32x16_bf16(a0, bf, sa, 0, 0, 0);
        }
#pragma unroll
        for (int g = 0; g < 4; ++g)
#pragma unroll
          for (int i = 0; i < 4; ++i)
            sS[(rt * 32 + 8 * g + 4 * half + i) * 66 + ct * 32 + n32] = fmaxf(sa[4 * g + i], 0.0f);
      }
      __syncthreads();  // B6

      // ===== row softmax -> sSup (all 1024 threads, 16 per row) =====
      {
        int row = tid >> 4, ci = (tid & 15) * 4;
        float2 v01 = *(const float2*)(sS + row * 66 + ci);
        float2 v23 = *(const float2*)(sS + row * 66 + ci + 2);
        float s0 = v01.x, s1 = v01.y, s2 = v23.x, s3 = v23.y;
        float mx = fmaxf(fmaxf(s0, s1), fmaxf(s2, s3));
#pragma unroll
        for (int off = 1; off < 16; off <<= 1) mx = fmaxf(mx, __shfl_xor(mx, off, 16));
        float e0 = __expf(s0 - mx), e1 = __expf(s1 - mx);
        float e2 = __expf(s2 - mx), e3 = __expf(s3 - mx);
        float sum = e0 + e1 + e2 + e3;
#pragma unroll
        for (int off = 1; off < 16; off <<= 1) sum += __shfl_xor(sum, off, 16);
        float inv = 1.0f / sum;
        *(uint2*)(sSup + row * 68 + ci) = pack4(e0 * inv, e1 * inv, e2 * inv, e3 * inv);
      }
      __syncthreads();  // B7
    }  // t
    __syncthreads();
  }  // layer
}

extern "C" void kernel_launch(void* const* d_in, const int* in_sizes, int n_in,
                              void* d_out, int out_size, void* d_ws, size_t ws_size,
                              hipStream_t stream) {
  const float* Xin  = (const float*)d_in[0];
  const float* H0   = (const float*)d_in[1];
  const float* Sup0 = (const float*)d_in[2];
  const float* Wg0  = (const float*)d_in[3];
  const float* bg0  = (const float*)d_in[4];
  const float* Wc0  = (const float*)d_in[5];
  const float* bc0  = (const float*)d_in[6];
  const float* Wq0  = (const float*)d_in[7];
  const float* Wk0  = (const float*)d_in[8];
  const float* Wg1  = (const float*)d_in[9];
  const float* bg1  = (const float*)d_in[10];
  const float* Wc1  = (const float*)d_in[11];
  const float* bc1  = (const float*)d_in[12];
  const float* Wq1  = (const float*)d_in[13];
  const float* Wk1  = (const float*)d_in[14];
  unsigned short* Wp = (unsigned short*)d_ws;

  hipFuncSetAttribute(reinterpret_cast<const void*>(sglc_main),
                      hipFuncAttributeMaxDynamicSharedMemorySize, LDS_USHORTS * 2);

  hipLaunchKernelGGL(sglc_pack, dim3(1792), dim3(256), 0, stream,
                     Wg0, Wc0, Wq0, Wk0, Wg1, Wc1, Wq1, Wk1, Wp);
  hipLaunchKernelGGL(sglc_main, dim3(BB), dim3(1024), LDS_USHORTS * 2, stream,
                     Xin, H0, Sup0, bg0, bc0, bg1, bc1, Wp, (float*)d_out);
}